// Round 9
// baseline (2100.873 us; speedup 1.0000x reference)
//
#include <hip/hip_runtime.h>
#include <math.h>

#define T_ 16
#define B_ 128
#define C3 24
#define OUT_ 64
#define EPS_ 1e-5f
#define TRS 776      // t2 row stride (shorts)
#define PTS 36       // PT per-r stride (shorts)

typedef __attribute__((ext_vector_type(8))) short bf16x8;
typedef __attribute__((ext_vector_type(4))) float f32x4;

union FragU { unsigned u[4]; bf16x8 f; };

__device__ __forceinline__ short f2bf(float x) {
    unsigned u = __float_as_uint(x);
    return (short)((u + 0x7fffu + ((u >> 16) & 1u)) >> 16);
}
__device__ __forceinline__ unsigned packsplit(float x) {
    unsigned u = __float_as_uint(x);
    unsigned h = (u + 0x7fffu + ((u >> 16) & 1u)) & 0xffff0000u;
    float r = x - __uint_as_float(h);
    unsigned v = __float_as_uint(r);
    unsigned l = (v + 0x7fffu + ((v >> 16) & 1u)) >> 16;
    return h | l;
}
__device__ __forceinline__ void unpack_frags(const unsigned* p, bf16x8& hi, bf16x8& lo) {
    FragU H, L;
#pragma unroll
    for (int q = 0; q < 4; ++q) {
        H.u[q] = (p[2*q] >> 16) | (p[2*q+1] & 0xffff0000u);
        L.u[q] = (p[2*q] & 0xffffu) | (p[2*q+1] << 16);
    }
    hi = H.f; lo = L.f;
}
__device__ __forceinline__ f32x4 mfma16(bf16x8 a, bf16x8 b, f32x4 c) {
    return __builtin_amdgcn_mfma_f32_16x16x32_bf16(a, b, c, 0, 0, 0);
}

// ---------- prep: Wr -> B-fragment-major hi/lo planes (per-d mini-GEMMs) ----------
__global__ void prep_wrB(const float* __restrict__ Wr, short* __restrict__ H, short* __restrict__ L) {
    int idx = blockIdx.x * 256 + threadIdx.x;
    if (idx >= 884736) return;
    int jj = idx & 7, lane = (idx >> 3) & 63, f = idx >> 9;
    int kf = f % 3, rt = (f / 3) % 6, d = f / 18;
    int col = lane & 15, grp = lane >> 4;
    int e = kf * 32 + grp * 8 + jj;
    int r = rt * 16 + col;
    float x = Wr[(size_t)(d * 96 + e) * 96 + r];
    unsigned u = __float_as_uint(x);
    unsigned hb = (u + 0x7fffu + ((u >> 16) & 1u)) & 0xffff0000u;
    float res = x - __uint_as_float(hb);
    unsigned v = __float_as_uint(res);
    H[idx] = (short)(hb >> 16);
    L[idx] = (short)((v + 0x7fffu + ((v >> 16) & 1u)) >> 16);
}
// ---------- prep: W2 -> B-fragment-major hi/lo planes ----------
__global__ void prep_w2f(const float* __restrict__ W2, short* __restrict__ Fhi, short* __restrict__ Flo) {
    int idx = blockIdx.x * 256 + threadIdx.x;
    if (idx >= 73728) return;
    int j = idx & 7, lane = (idx >> 3) & 63, kb = (idx >> 9) % 24, rt = idx / (512 * 24);
    int col = lane & 15, grp = lane >> 4;
    int f = rt * 16 + col, k = kb * 32 + grp * 8 + j;
    float x = W2[(size_t)k * 96 + f];
    unsigned u = __float_as_uint(x);
    unsigned h = (u + 0x7fffu + ((u >> 16) & 1u)) & 0xffff0000u;
    float res = x - __uint_as_float(h);
    unsigned v = __float_as_uint(res);
    Fhi[idx] = (short)(h >> 16);
    Flo[idx] = (short)((v + 0x7fffu + ((v >> 16) & 1u)) >> 16);
}
// ---------- prep: y0 = sum_n rel_bias @ Wr (fp32), 64-block atomic ----------
__global__ __launch_bounds__(768, 1) void y0_kernel(const float* __restrict__ rel_bias,
                                                    const float* __restrict__ Wr,
                                                    float* __restrict__ y0) {
    __shared__ float s[768];
    const int n = blockIdx.x >> 3, sl = blockIdx.x & 7;
    const int tid = threadIdx.x;
    const int r = tid % 96, p = tid / 96;
    const float* rb = rel_bias + n * 9216 + sl * 1152;
    float acc = 0.f;
    for (int i = p * 144; i < p * 144 + 144; ++i)
        acc += rb[i] * Wr[(size_t)(sl * 1152 + i) * 96 + r];
    s[tid] = acc;
    __syncthreads();
    if (tid < 96) {
        float tot = 0.f;
        for (int q = 0; q < 8; ++q) tot += s[q * 96 + tid];
        atomicAdd(&y0[n * 96 + tid], tot);
    }
}

// ================= fused: waves 0-5 recurrence, waves 6-11 output pipeline =================
__global__ __launch_bounds__(768, 3) void stm_fused(
    const float* __restrict__ x, const float* __restrict__ Wqkv, const float* __restrict__ bqkv,
    const float* __restrict__ ln_g, const float* __restrict__ ln_b,
    const float* __restrict__ a1p, const float* __restrict__ a2p, const float* __restrict__ a3p,
    const float* __restrict__ b2, const float* __restrict__ br,
    const float* __restrict__ W3, const float* __restrict__ b3,
    const float* __restrict__ item_bias, const float* __restrict__ rel_bias,
    const float* __restrict__ y0g,
    const short* __restrict__ WrBH, const short* __restrict__ WrBL,
    const short* __restrict__ W2H, const short* __restrict__ W2L,
    float* __restrict__ out)
{
    __shared__ float s_Wq[2304], s_lng[2304], s_lnb[2304];
    __shared__ float s_Q[2304];
    __shared__ __attribute__((aligned(16))) float s_scr[2304];
    __shared__ __attribute__((aligned(16))) unsigned s_tP[8 * 776];   // split t [j][n*96+d]
    __shared__ __attribute__((aligned(16))) short s_t2[2][8 * TRS];   // bf16 t [n][d*8+j]
    __shared__ __attribute__((aligned(16))) float s_vb[2][768];       // v [j][e]
    __shared__ float s_tsum[768], s_G[768], s_y[768];
    __shared__ __attribute__((aligned(16))) short s_PT[6][3456];      // per-D-wave P slice [r][36]
    __shared__ float s_xt[96], s_Vtr[96], s_br[96], s_b2v[96];
    __shared__ float s_p384[384];
    __shared__ float s_outp[384];
    __shared__ float s_xtWq[24], s_GWq[192], s_b2Wq[24], s_bq[24];
    __shared__ float s_red[32];
    __shared__ int s_bar, d_bar, s_pub, d_done;

    const int tid = threadIdx.x;
    const int b = blockIdx.x;
    const int wv = tid >> 6, lane = tid & 63, col = lane & 15, grp = lane >> 4;
    const float a1 = a1p[0], a2 = a2p[0], a3 = a3p[0];

    // ---- init (block-wide; __syncthreads allowed only here) ----
    if (tid == 0) { s_bar = 0; d_bar = 0; s_pub = 0; d_done = 0; }
    for (int i = tid; i < 2304; i += 768) {
        s_Wq[i] = Wqkv[i]; s_lng[i] = ln_g[i]; s_lnb[i] = ln_b[i];
    }
    if (tid < 24) s_bq[tid] = bqkv[tid];
    if (tid < 96) { s_br[tid] = br[tid]; s_b2v[tid] = b2[tid]; }
    if (tid >= 384) { int dt = tid - 384; s_y[dt] = y0g[dt]; s_y[dt + 384] = y0g[dt + 384]; }

    // S-state: thread (tid<384) owns row de, cols [ef0, ef0+24)
    const int de = tid >> 2, q4i = tid & 3, ef0 = q4i * 24;
    float rMi[24], rS[24];
    if (tid < 384) {
#pragma unroll
        for (int ii = 0; ii < 24; ++ii) {
            int idx = de * 96 + ef0 + ii;
            rMi[ii] = item_bias[idx];
            float ss = 0.f;
            for (int n = 0; n < 8; ++n) ss += rel_bias[n * 9216 + idx];
            rS[ii] = ss;
        }
    }
    __syncthreads();
    // Q0 = item_bias @ Wq (all threads), b2Wq
    for (int pp = 0; pp < 3; ++pp) {
        int o = tid + 768 * pp; int i = o / C3, c = o % C3;
        float acc = 0.f;
        const float* ib = item_bias + i * 96;
        for (int k = 0; k < 96; ++k) acc += ib[k] * s_Wq[k * C3 + c];
        s_Q[o] = acc;
    }
    { int c = tid % C3, p = tid / C3; float acc = 0.f;
      for (int k = 3 * p; k < 3 * p + 3; ++k) acc += s_b2v[k] * s_Wq[k * C3 + c];
      s_scr[tid % 2304] = 0.f; // no-op placeholder for safety
      s_scr[tid] = acc; }
    __syncthreads();
    if (tid < C3) { float a = 0.f; for (int p = 0; p < 32; ++p) a += s_scr[p * C3 + tid]; s_b2Wq[tid] = a; }
    __syncthreads();

    if (wv < 6) {
        // ======================= S role: recurrence =======================
        int scall = 0;
        volatile int* vsb = &s_bar;
        volatile int* vdd = &d_done;
        auto SBAR = [&]() {
            ++scall;
            __threadfence_block();
            if (lane == 0) atomicAdd(&s_bar, 1);
            while (*vsb < 6 * scall) {}
            __threadfence_block();
        };
        for (int t = 0; t < T_; ++t) {
            // P1: xt
            if (tid < 96) s_xt[tid] = x[((size_t)t * B_ + b) * 96 + tid];
            SBAR();
            // P2: Mi += xt xt^T ; xtWq partials
            {
                float xde = s_xt[de];
                const float4* xp = (const float4*)&s_xt[ef0];
#pragma unroll
                for (int v4 = 0; v4 < 6; ++v4) {
                    float4 xx = xp[v4];
                    rMi[v4 * 4 + 0] += xde * xx.x; rMi[v4 * 4 + 1] += xde * xx.y;
                    rMi[v4 * 4 + 2] += xde * xx.z; rMi[v4 * 4 + 3] += xde * xx.w;
                }
            }
            { int c = tid % C3, p = tid / C3; float acc = 0.f;
              for (int k = p * 6; k < p * 6 + 6; ++k) acc += s_xt[k] * s_Wq[k * C3 + c];
              s_p384[tid] = acc; }
            SBAR();
            // P3: xtWq final ; Vtr partials (shfl over 16-de groups)
            if (tid < C3) { float a = 0.f; for (int p = 0; p < 16; ++p) a += s_p384[p * C3 + tid]; s_xtWq[tid] = a; }
            {
                float pr[24];
#pragma unroll
                for (int ii = 0; ii < 24; ++ii) {
                    float v = rMi[ii] * rS[ii];
                    v += __shfl_xor(v, 4); v += __shfl_xor(v, 8);
                    v += __shfl_xor(v, 16); v += __shfl_xor(v, 32);
                    pr[ii] = v;
                }
                if ((lane >> 2) == 0) {
#pragma unroll
                    for (int ii = 0; ii < 24; ++ii)
                        s_scr[wv * 96 + lane * 24 + ii] = pr[ii];
                }
            }
            SBAR();
            // P4: Vtr final ; Q += xt (x) xtWq
            if (tid < 96) { float a = 0.f; for (int w = 0; w < 6; ++w) a += s_scr[w * 96 + tid]; s_Vtr[tid] = a; }
            for (int pp = 0; pp < 6; ++pp) { int o = tid + 384 * pp; int i = o / C3, c = o % C3;
                s_Q[o] += s_xt[i] * s_xtWq[c]; }
            SBAR();
            // P5: qkv_pre + LN sums
            {
                float ls = 0.f, lq = 0.f;
                for (int pp = 0; pp < 6; ++pp) {
                    int o = tid + 384 * pp; int i = o / C3, c = o % C3;
                    float qv = s_Q[o] + a2 * s_Vtr[i] * s_xtWq[c] + s_bq[c];
                    s_scr[o] = qv; ls += qv; lq += qv * qv;
                }
                for (int off = 32; off > 0; off >>= 1) { ls += __shfl_down(ls, off); lq += __shfl_down(lq, off); }
                if (lane == 0) { s_red[wv] = ls; s_red[16 + wv] = lq; }
            }
            SBAR();
            // P6/7: LN apply (mu/rstd redundantly)
            {
                float S = 0.f, Qs = 0.f;
                for (int w = 0; w < 6; ++w) { S += s_red[w]; Qs += s_red[16 + w]; }
                float mu = S * (1.0f / 2304.f);
                float rstd = rsqrtf(Qs * (1.0f / 2304.f) - mu * mu + EPS_);
                for (int pp = 0; pp < 6; ++pp) {
                    int o = tid + 384 * pp;
                    s_scr[o] = (s_scr[o] - mu) * rstd * s_lng[o] + s_lnb[o];
                }
            }
            SBAR();
            // wait for D to have released buffer parity t&1 (it held step t-2)
            while (*vdd < t - 1) {}
            __threadfence_block();
            // P8: v + t into buffers parity p
            {
                const int p = t & 1;
#pragma unroll
                for (int half = 0; half < 2; ++half) {
                    int idx = tid + 384 * half;
                    int jv = idx / 96, ev = idx % 96;
                    s_vb[p][idx] = s_scr[ev * C3 + 16 + jv];
                }
#pragma unroll
                for (int half = 0; half < 2; ++half) {
                    int idx = tid + 384 * half;
                    int j = idx / 96, d = idx % 96;
                    float kk = s_scr[d * C3 + 8 + j];
                    float ts = 0.f;
#pragma unroll
                    for (int n = 0; n < 8; ++n) {
                        float tv = tanhf(s_scr[d * C3 + n] * kk);
                        ts += tv;
                        unsigned up = packsplit(tv);
                        s_tP[j * 776 + n * 96 + d] = up;
                        s_t2[p][n * TRS + d * 8 + j] = (short)(up >> 16);
                    }
                    s_tsum[j * 96 + d] = ts;
                }
            }
            SBAR();
            if (tid == 0) atomicExch(&s_pub, t + 1);   // publish step t
            // P9: G-GEMM (wave wv = rt, 24 kb, 4-term split)
            {
                const int rt = wv;
                f32x4 accG = {0.f, 0.f, 0.f, 0.f};
                for (int kb = 0; kb < 24; ++kb) {
                    unsigned pa[8] = {0,0,0,0,0,0,0,0};
                    if (col < 8) {
                        const uint4* q0 = (const uint4*)&s_tP[col * 776 + kb * 32 + grp * 8];
                        uint4 x0 = q0[0], x1 = q0[1];
                        pa[0]=x0.x; pa[1]=x0.y; pa[2]=x0.z; pa[3]=x0.w;
                        pa[4]=x1.x; pa[5]=x1.y; pa[6]=x1.z; pa[7]=x1.w;
                    }
                    bf16x8 ah, al; unpack_frags(pa, ah, al);
                    int fo = ((rt * 24 + kb) * 64 + lane) * 8;
                    bf16x8 bh = *(const bf16x8*)&W2H[fo];
                    bf16x8 bl = *(const bf16x8*)&W2L[fo];
                    accG = mfma16(ah, bh, accG);
                    accG = mfma16(al, bh, accG);
                    accG = mfma16(ah, bl, accG);
                    accG = mfma16(al, bl, accG);
                }
                if (grp < 2) {
#pragma unroll
                    for (int reg = 0; reg < 4; ++reg)
                        s_G[(grp * 4 + reg) * 96 + rt * 16 + col] = accG[reg];
                }
            }
            SBAR();
            // P10: GWq partials + S/Mi register updates
            { int oo = tid % 192, hf = tid / 192; int jg = oo / C3, cc = oo % C3;
              float a = 0.f;
              for (int f = hf * 48; f < hf * 48 + 48; ++f) a += s_G[jg * 96 + f] * s_Wq[f * C3 + cc];
              s_p384[tid] = a; }
            {
                const int p = t & 1;
                float tj[8], vj[8];
#pragma unroll
                for (int j = 0; j < 8; ++j) { tj[j] = s_tsum[j * 96 + de]; vj[j] = s_vb[p][j * 96 + de]; }
#pragma unroll
                for (int h2 = 0; h2 < 2; ++h2) {
                    const int cb = ef0 + h2 * 12;
                    float sn[12], r2[12];
#pragma unroll
                    for (int ii = 0; ii < 12; ++ii) { sn[ii] = 0.f; r2[ii] = s_b2v[cb + ii]; }
#pragma unroll
                    for (int j = 0; j < 8; ++j) {
                        const float4* vp = (const float4*)&s_vb[p][j * 96 + cb];
                        const float4* gp = (const float4*)&s_G[j * 96 + cb];
#pragma unroll
                        for (int v4 = 0; v4 < 3; ++v4) {
                            float4 vv = vp[v4], gg = gp[v4];
                            sn[v4*4+0] += tj[j]*vv.x; sn[v4*4+1] += tj[j]*vv.y;
                            sn[v4*4+2] += tj[j]*vv.z; sn[v4*4+3] += tj[j]*vv.w;
                            r2[v4*4+0] += vj[j]*gg.x; r2[v4*4+1] += vj[j]*gg.y;
                            r2[v4*4+2] += vj[j]*gg.z; r2[v4*4+3] += vj[j]*gg.w;
                        }
                    }
#pragma unroll
                    for (int ii = 0; ii < 12; ++ii) {
                        rS[h2 * 12 + ii] = a1 * rS[h2 * 12 + ii] + sn[ii];
                        rMi[h2 * 12 + ii] += a3 * r2[ii];
                    }
                }
            }
            SBAR();
            // P11: GWq final
            if (tid < 192) s_GWq[tid] = s_p384[tid] + s_p384[192 + tid];
            SBAR();
            // P12: Q += a3*(v^T GWq + b2Wq)
            {
                const int p = t & 1;
                for (int pp = 0; pp < 6; ++pp) {
                    int o = tid + 384 * pp; int i = o / C3, c = o % C3;
                    float a = s_b2Wq[c];
#pragma unroll
                    for (int j = 0; j < 8; ++j) a += s_vb[p][j * 96 + i] * s_GWq[j * C3 + c];
                    s_Q[o] += a3 * a;
                }
            }
        }
    } else {
        // ======================= D role: Δy / y / out =======================
        const int dt = tid - 384;
        const int dw = dt >> 6;
        int dcall = 0;
        volatile int* vdb = &d_bar;
        volatile int* vsp = &s_pub;
        auto DBAR = [&]() {
            ++dcall;
            __threadfence_block();
            if (lane == 0) atomicAdd(&d_bar, 1);
            while (*vdb < 6 * dcall) {}
            __threadfence_block();
        };
        short* PTs = s_PT[dw];
        float* Dsl = (float*)PTs;              // own slice as float scratch (1728 floats)
        float* Dall = (float*)s_PT;            // slices at stride 1728 floats

        for (int s = 0; s < T_; ++s) {
            while (*vsp < s + 1) {}
            __threadfence_block();
            const int p = s & 1;
            // A-frags from v
            bf16x8 Av[3];
#pragma unroll
            for (int kf = 0; kf < 3; ++kf) {
                FragU F;
                if (col < 8) {
                    const float* vp = &s_vb[p][col * 96 + kf * 32 + grp * 8];
#pragma unroll
                    for (int qq = 0; qq < 4; ++qq)
                        F.u[qq] = (unsigned)(unsigned short)f2bf(vp[2*qq]) |
                                  ((unsigned)(unsigned short)f2bf(vp[2*qq+1]) << 16);
                } else { F.u[0]=F.u[1]=F.u[2]=F.u[3]=0; }
                Av[kf] = F.f;
            }
            f32x4 accD[6];
#pragma unroll
            for (int rt = 0; rt < 6; ++rt) accD[rt] = (f32x4){0.f,0.f,0.f,0.f};

            for (int g4 = 0; g4 < 4; ++g4) {
#pragma unroll
                for (int dl = 0; dl < 4; ++dl) {
                    const int d = dw * 16 + g4 * 4 + dl;
                    f32x4 aP[6];
#pragma unroll
                    for (int rt = 0; rt < 6; ++rt) aP[rt] = (f32x4){0.f,0.f,0.f,0.f};
#pragma unroll
                    for (int kf = 0; kf < 3; ++kf)
#pragma unroll
                        for (int rt = 0; rt < 6; ++rt) {
                            size_t fo = ((size_t)(d * 18 + rt * 3 + kf) * 64 + lane) * 8;
                            bf16x8 bh = *(const bf16x8*)&WrBH[fo];
                            bf16x8 bl = *(const bf16x8*)&WrBL[fo];
                            aP[rt] = mfma16(Av[kf], bh, aP[rt]);
                            aP[rt] = mfma16(Av[kf], bl, aP[rt]);
                        }
                    if (grp < 2) {
#pragma unroll
                        for (int rt = 0; rt < 6; ++rt) {
                            int base = (rt * 16 + col) * PTS + dl * 8 + grp * 4;
                            *(unsigned*)&PTs[base] =
                                (unsigned)(unsigned short)f2bf(aP[rt][0]) |
                                ((unsigned)(unsigned short)f2bf(aP[rt][1]) << 16);
                            *(unsigned*)&PTs[base + 2] =
                                (unsigned)(unsigned short)f2bf(aP[rt][2]) |
                                ((unsigned)(unsigned short)f2bf(aP[rt][3]) << 16);
                        }
                    }
                }
                // GEMM2 for this 4-d group
                FragU A2;
                if (col < 8) {
                    uint4 z = *(const uint4*)&s_t2[p][col * TRS + (dw * 16 + g4 * 4) * 8 + grp * 8];
                    A2.u[0] = z.x; A2.u[1] = z.y; A2.u[2] = z.z; A2.u[3] = z.w;
                } else { A2.u[0]=A2.u[1]=A2.u[2]=A2.u[3]=0; }
#pragma unroll
                for (int rt = 0; rt < 6; ++rt) {
                    FragU Bf;
                    const uint2* pb = (const uint2*)&PTs[(rt * 16 + col) * PTS + grp * 8];
                    uint2 z0 = pb[0], z1 = pb[1];
                    Bf.u[0] = z0.x; Bf.u[1] = z0.y; Bf.u[2] = z1.x; Bf.u[3] = z1.y;
                    accD[rt] = mfma16(A2.f, Bf.f, accD[rt]);
                }
            }
            // Δy partial into own slice
            if (grp < 2) {
#pragma unroll
                for (int rt = 0; rt < 6; ++rt)
#pragma unroll
                    for (int reg = 0; reg < 4; ++reg)
                        Dsl[(grp * 4 + reg) * 96 + rt * 16 + col] = accD[rt][reg];
            }
            DBAR();
            if (dt == 0) atomicExch(&d_done, s + 1);   // release buffers of step s
            // y update + r_vec (rv at slice0 floats [768..1536))
            {
#pragma unroll
                for (int half = 0; half < 2; ++half) {
                    int i = dt + 384 * half;
                    float acc = 0.f;
#pragma unroll
                    for (int w6 = 0; w6 < 6; ++w6) acc += Dall[w6 * 1728 + i];
                    float ny = a1 * s_y[i] + acc;
                    s_y[i] = ny;
                    Dall[768 + i] = ny + s_br[i % 96];
                }
            }
            DBAR();
            // out partials
            {
                int o = dt & 63, ch = dt >> 6;
                float a = 0.f;
                for (int ii = 0; ii < 128; ++ii) {
                    int i = ch * 128 + ii;
                    a += Dall[768 + i] * W3[(size_t)i * 64 + o];
                }
                s_outp[dt] = a;
            }
            DBAR();
            if (dt < 64) {
                float a = b3[dt];
#pragma unroll
                for (int ch = 0; ch < 6; ++ch) a += s_outp[ch * 64 + dt];
                out[((size_t)(s * B_ + b)) * OUT_ + dt] = a;
            }
        }
    }
}

extern "C" void kernel_launch(void* const* d_in, const int* in_sizes, int n_in,
                              void* d_out, int out_size, void* d_ws, size_t ws_size,
                              hipStream_t stream) {
    const float* x         = (const float*)d_in[0];
    const float* Wqkv      = (const float*)d_in[1];
    const float* bqkv      = (const float*)d_in[2];
    const float* ln_g      = (const float*)d_in[3];
    const float* ln_b      = (const float*)d_in[4];
    const float* a1        = (const float*)d_in[5];
    const float* a2        = (const float*)d_in[6];
    const float* a3        = (const float*)d_in[7];
    const float* W2        = (const float*)d_in[8];
    const float* b2        = (const float*)d_in[9];
    const float* Wr        = (const float*)d_in[10];
    const float* br        = (const float*)d_in[11];
    const float* W3        = (const float*)d_in[12];
    const float* b3        = (const float*)d_in[13];
    const float* item_bias = (const float*)d_in[14];
    const float* rel_bias  = (const float*)d_in[15];
    float* out = (float*)d_out;

    char* ws = (char*)d_ws;
    short* WrBH = (short*)ws;                          // 1,769,472 B
    short* WrBL = (short*)(ws + 1769472);              // 1,769,472 B
    short* W2H  = (short*)(ws + 3538944);              //   147,456 B
    short* W2L  = (short*)(ws + 3686400);              //   147,456 B
    float* y0   = (float*)(ws + 3833856);              //     3,072 B

    hipMemsetAsync(y0, 0, 3072, stream);
    hipLaunchKernelGGL(prep_wrB, dim3(3456), dim3(256), 0, stream, Wr, WrBH, WrBL);
    hipLaunchKernelGGL(prep_w2f, dim3(288), dim3(256), 0, stream, W2, W2H, W2L);
    hipLaunchKernelGGL(y0_kernel, dim3(64), dim3(768), 0, stream, rel_bias, Wr, y0);
    hipLaunchKernelGGL(stm_fused, dim3(B_), dim3(768), 0, stream,
                       x, Wqkv, bqkv, ln_g, ln_b, a1, a2, a3,
                       b2, br, W3, b3, item_bias, rel_bias,
                       y0, WrBH, WrBL, W2H, W2L, out);
}

// Round 10
// 1384.143 us; speedup vs baseline: 1.5178x; 1.5178x over previous
//
#include <hip/hip_runtime.h>
#include <math.h>

#define T_ 16
#define B_ 128
#define C3 24
#define OUT_ 64
#define EPS_ 1e-5f

typedef __attribute__((ext_vector_type(8))) short bf16x8;
typedef __attribute__((ext_vector_type(4))) float f32x4;

union FragU { unsigned u[4]; bf16x8 f; };

__device__ __forceinline__ short f2bf(float x) {
    unsigned u = __float_as_uint(x);
    return (short)((u + 0x7fffu + ((u >> 16) & 1u)) >> 16);
}
__device__ __forceinline__ unsigned packsplit(float x) {
    unsigned u = __float_as_uint(x);
    unsigned h = (u + 0x7fffu + ((u >> 16) & 1u)) & 0xffff0000u;
    float r = x - __uint_as_float(h);
    unsigned v = __float_as_uint(r);
    unsigned l = (v + 0x7fffu + ((v >> 16) & 1u)) >> 16;
    return h | l;
}
__device__ __forceinline__ void unpack_frags(const unsigned* p, bf16x8& hi, bf16x8& lo) {
    FragU H, L;
#pragma unroll
    for (int q = 0; q < 4; ++q) {
        H.u[q] = (p[2*q] >> 16) | (p[2*q+1] & 0xffff0000u);
        L.u[q] = (p[2*q] & 0xffffu) | (p[2*q+1] << 16);
    }
    hi = H.f; lo = L.f;
}
__device__ __forceinline__ f32x4 mfma16(bf16x8 a, bf16x8 b, f32x4 c) {
    return __builtin_amdgcn_mfma_f32_16x16x32_bf16(a, b, c, 0, 0, 0);
}
__device__ __forceinline__ void splitf(float x, short& h, short& l) {
    unsigned u = __float_as_uint(x);
    unsigned hb = (u + 0x7fffu + ((u >> 16) & 1u)) & 0xffff0000u;
    float res = x - __uint_as_float(hb);
    unsigned v = __float_as_uint(res);
    h = (short)(hb >> 16);
    l = (short)((v + 0x7fffu + ((v >> 16) & 1u)) >> 16);
}

// ---------- prep: Wr -> B-fragment-major hi/lo planes, per-d mini-GEMMs ----------
__global__ void prep_wrB(const float* __restrict__ Wr, short* __restrict__ H, short* __restrict__ L) {
    int idx = blockIdx.x * 256 + threadIdx.x;
    if (idx >= 884736) return;
    int jj = idx & 7, lane = (idx >> 3) & 63, f = idx >> 9;
    int kf = f % 3, rt = (f / 3) % 6, d = f / 18;
    int col = lane & 15, grp = lane >> 4;
    int e = kf * 32 + grp * 8 + jj;
    int r = rt * 16 + col;
    short h, l; splitf(Wr[(size_t)(d * 96 + e) * 96 + r], h, l);
    H[idx] = h; L[idx] = l;
}
// ---------- prep: W2 -> B-fragment-major hi/lo planes ----------
__global__ void prep_w2f(const float* __restrict__ W2, short* __restrict__ Fhi, short* __restrict__ Flo) {
    int idx = blockIdx.x * 256 + threadIdx.x;
    if (idx >= 73728) return;
    int j = idx & 7, lane = (idx >> 3) & 63, kb = (idx >> 9) % 24, rt = idx / (512 * 24);
    int col = lane & 15, grp = lane >> 4;
    int f = rt * 16 + col, k = kb * 32 + grp * 8 + j;
    short h, l; splitf(W2[(size_t)k * 96 + f], h, l);
    Fhi[idx] = h; Flo[idx] = l;
}
// ---------- prep: W3 -> B-fragment-major hi/lo planes ----------
__global__ void prep_w3f(const float* __restrict__ W3, short* __restrict__ H, short* __restrict__ L) {
    int idx = blockIdx.x * 256 + threadIdx.x;
    if (idx >= 49152) return;
    int jj = idx & 7, lane = (idx >> 3) & 63, kb = (idx >> 9) % 24, ot = idx / (512 * 24);
    int col = lane & 15, grp = lane >> 4;
    int k = kb * 32 + grp * 8 + jj, o = ot * 16 + col;
    short h, l; splitf(W3[(size_t)k * 64 + o], h, l);
    H[idx] = h; L[idx] = l;
}
// ---------- prep: y0 = sum_n rel_bias @ Wr (fp32), 64-block atomic ----------
__global__ __launch_bounds__(768, 1) void y0_kernel(const float* __restrict__ rel_bias,
                                                    const float* __restrict__ Wr,
                                                    float* __restrict__ y0) {
    __shared__ float s[768];
    const int n = blockIdx.x >> 3, sl = blockIdx.x & 7;
    const int tid = threadIdx.x;
    const int r = tid % 96, p = tid / 96;
    const float* rb = rel_bias + n * 9216 + sl * 1152;
    float acc = 0.f;
    for (int i = p * 144; i < p * 144 + 144; ++i)
        acc += rb[i] * Wr[(size_t)(sl * 1152 + i) * 96 + r];
    s[tid] = acc;
    __syncthreads();
    if (tid < 96) {
        float tot = 0.f;
        for (int q = 0; q < 8; ++q) tot += s[q * 96 + tid];
        atomicAdd(&y0[n * 96 + tid], tot);
    }
}
// ---------- prep: c0 = y0@W3, cbr = br@W3 + b3 ----------
__global__ __launch_bounds__(256, 1) void c0_kernel(const float* __restrict__ y0,
                                                    const float* __restrict__ br,
                                                    const float* __restrict__ W3,
                                                    const float* __restrict__ b3,
                                                    float* __restrict__ c0,
                                                    float* __restrict__ cbr) {
    __shared__ float sp[512];
    const int tid = threadIdx.x;
    const int o = tid & 63, q = tid >> 6;
    float a = 0.f, c = 0.f;
    for (int i = q * 192; i < q * 192 + 192; ++i) {
        float w = W3[(size_t)i * 64 + o];
        a += y0[i] * w;
        c += br[i % 96] * w;
    }
    sp[tid] = a; sp[256 + tid] = c;
    __syncthreads();
    if (tid < 64) {
        float aa = 0.f, cc = 0.f;
        for (int qq = 0; qq < 4; ++qq) { aa += sp[qq * 64 + tid]; cc += sp[256 + qq * 64 + tid]; }
        c0[tid] = aa;
        cbr[tid] = cc + b3[tid];
    }
}

// ================= Kernel A: recurrence only, 1 block per batch =================
__global__ __launch_bounds__(768, 2) void stm_rec(
    const float* __restrict__ x, const float* __restrict__ Wqkv, const float* __restrict__ bqkv,
    const float* __restrict__ ln_g, const float* __restrict__ ln_b,
    const float* __restrict__ a1p, const float* __restrict__ a2p, const float* __restrict__ a3p,
    const float* __restrict__ b2,
    const float* __restrict__ item_bias, const float* __restrict__ rel_bias,
    const short* __restrict__ W2H, const short* __restrict__ W2L,
    short* __restrict__ t2g, short* __restrict__ vgb)
{
    __shared__ float s_xall[1536];                                  // all 16 xt
    __shared__ __attribute__((aligned(16))) float s_scr[2304];      // qkv (+Vtr partials at [768..))
    __shared__ float s_scrA[768];                                   // xtWq partials
    __shared__ float s_scrB[768];                                   // GWq partials
    __shared__ __attribute__((aligned(16))) unsigned s_tP[8 * 776]; // split t [j][n*96+d]
    __shared__ __attribute__((aligned(16))) short s_t2L[6144];      // bf16 t [n][d*8+j]
    __shared__ float s_Wq[2304], s_lng[2304], s_lnb[2304];
    __shared__ float s_tsum[768], s_v[768];
    __shared__ float s_G0[768], s_G1[768];
    __shared__ float s_xtWq[24], s_b2Wq[24], s_bq[24];
    __shared__ float s_b2v[96], s_Vtr[96];
    __shared__ float s_red[32];

    const int tid = threadIdx.x;
    const int b = blockIdx.x;
    const int wv = tid >> 6, lane = tid & 63, col = lane & 15, grp = lane >> 4;
    const float a1 = a1p[0], a2 = a2p[0], a3 = a3p[0];

    // register state
    const int de = tid >> 3, ef0 = (tid & 7) * 12;
    float rMi[12], rS[12], rb2[12], rQ[3];
#pragma unroll
    for (int ii = 0; ii < 12; ++ii) {
        int idx = de * 96 + ef0 + ii;
        rMi[ii] = item_bias[idx];
        float ss = 0.f;
        for (int n = 0; n < 8; ++n) ss += rel_bias[n * 9216 + idx];
        rS[ii] = ss;
        rb2[ii] = b2[ef0 + ii];
    }

    // ---- init ----
    for (int i = tid; i < 1536; i += 768)
        s_xall[i] = x[((size_t)(i / 96) * B_ + b) * 96 + (i % 96)];
    for (int i = tid; i < 2304; i += 768) {
        s_Wq[i] = Wqkv[i]; s_lng[i] = ln_g[i]; s_lnb[i] = ln_b[i];
    }
    if (tid < 24) s_bq[tid] = bqkv[tid];
    if (tid < 96) s_b2v[tid] = b2[tid];
    __syncthreads();
    // Q0 in regs
#pragma unroll
    for (int pp = 0; pp < 3; ++pp) {
        int o = tid + 768 * pp; int i = o / C3, c = o % C3;
        float acc = 0.f;
        const float* ib = item_bias + i * 96;
        for (int k = 0; k < 96; ++k) acc += ib[k] * s_Wq[k * C3 + c];
        rQ[pp] = acc;
    }
    { int c = tid % C3, p = tid / C3; float acc = 0.f;
      for (int k = 3 * p; k < 3 * p + 3; ++k) acc += s_b2v[k] * s_Wq[k * C3 + c];
      s_scrA[tid] = acc; }
    __syncthreads();
    if (tid < C3) { float a = 0.f; for (int p = 0; p < 32; ++p) a += s_scrA[p * C3 + tid]; s_b2Wq[tid] = a; }
    __syncthreads();

    for (int t = 0; t < T_; ++t) {
        const float* xt = s_xall + t * 96;
        // P2: Mi += xt xt^T (regs) ; xtWq partials
        {
            float xde = xt[de];
            const float4* xp = (const float4*)&xt[ef0];
            float4 x0 = xp[0], x1 = xp[1], x2 = xp[2];
            rMi[0] += xde * x0.x; rMi[1] += xde * x0.y; rMi[2] += xde * x0.z; rMi[3] += xde * x0.w;
            rMi[4] += xde * x1.x; rMi[5] += xde * x1.y; rMi[6] += xde * x1.z; rMi[7] += xde * x1.w;
            rMi[8] += xde * x2.x; rMi[9] += xde * x2.y; rMi[10] += xde * x2.z; rMi[11] += xde * x2.w;
        }
        { int c = tid % C3, p = tid / C3; float acc = 0.f;
          for (int k = 3 * p; k < 3 * p + 3; ++k) acc += xt[k] * s_Wq[k * C3 + c];
          s_scrA[tid] = acc; }
        __syncthreads();                                   // B1
        // P3: xtWq final ; Vtr partials (shfl)
        if (tid < C3) { float a = 0.f; for (int p = 0; p < 32; ++p) a += s_scrA[p * C3 + tid]; s_xtWq[tid] = a; }
        {
            float p12[12];
#pragma unroll
            for (int ii = 0; ii < 12; ++ii) p12[ii] = rMi[ii] * rS[ii];
#pragma unroll
            for (int ii = 0; ii < 12; ++ii) {
                p12[ii] += __shfl_xor(p12[ii], 8);
                p12[ii] += __shfl_xor(p12[ii], 16);
                p12[ii] += __shfl_xor(p12[ii], 32);
            }
            if ((lane >> 3) == 0) {
#pragma unroll
                for (int ii = 0; ii < 12; ++ii)
                    s_scr[768 + wv * 96 + (lane & 7) * 12 + ii] = p12[ii];
            }
        }
        __syncthreads();                                   // B2
        // P4: Vtr final ; rQ += xt (x) xtWq
        if (tid < 96) { float a = 0.f; for (int w = 0; w < 12; ++w) a += s_scr[768 + w * 96 + tid]; s_Vtr[tid] = a; }
#pragma unroll
        for (int pp = 0; pp < 3; ++pp) { int o = tid + 768 * pp; int i = o / C3, c = o % C3;
            rQ[pp] += xt[i] * s_xtWq[c]; }
        __syncthreads();                                   // B3
        // P5: qkv_pre + LN sums
        {
            float ls = 0.f, lq = 0.f;
#pragma unroll
            for (int pp = 0; pp < 3; ++pp) {
                int o = tid + 768 * pp; int i = o / C3, c = o % C3;
                float qv = rQ[pp] + a2 * s_Vtr[i] * s_xtWq[c] + s_bq[c];
                s_scr[o] = qv; ls += qv; lq += qv * qv;
            }
            for (int off = 32; off > 0; off >>= 1) { ls += __shfl_down(ls, off); lq += __shfl_down(lq, off); }
            if (lane == 0) { s_red[wv] = ls; s_red[16 + wv] = lq; }
        }
        __syncthreads();                                   // B4
        // P6/7: LN apply (redundant mu/rstd)
        {
            float S = 0.f, Qs = 0.f;
            for (int w = 0; w < 12; ++w) { S += s_red[w]; Qs += s_red[16 + w]; }
            float mu = S * (1.0f / 2304.f);
            float rstd = rsqrtf(Qs * (1.0f / 2304.f) - mu * mu + EPS_);
#pragma unroll
            for (int pp = 0; pp < 3; ++pp) {
                int o = tid + 768 * pp;
                s_scr[o] = (s_scr[o] - mu) * rstd * s_lng[o] + s_lnb[o];
            }
        }
        __syncthreads();                                   // B5
        // P8: v + t
        { int j = tid / 96, e = tid % 96;
          float vv = s_scr[e * C3 + 16 + j];
          s_v[tid] = vv;
          vgb[((size_t)(t * B_ + b)) * 768 + tid] = f2bf(vv); }
        {
            int j = tid / 96, d = tid % 96;
            float kk = s_scr[d * C3 + 8 + j];
            float ts = 0.f;
#pragma unroll
            for (int n = 0; n < 8; ++n) {
                float tv = tanhf(s_scr[d * C3 + n] * kk);
                ts += tv;
                unsigned up = packsplit(tv);
                s_tP[j * 776 + n * 96 + d] = up;
                s_t2L[n * 768 + d * 8 + j] = (short)(up >> 16);
            }
            s_tsum[j * 96 + d] = ts;
        }
        __syncthreads();                                   // B6
        // P9: dump t2 + G-GEMM (12 waves, 4 accumulators)
        *(uint4*)&t2g[((size_t)(t * B_ + b)) * 6144 + tid * 8] = *(const uint4*)&s_t2L[tid * 8];
        {
            const int rt = wv % 6, kh = wv / 6;
            f32x4 aHH = {0,0,0,0}, aLH = {0,0,0,0}, aHL = {0,0,0,0}, aLL = {0,0,0,0};
#pragma unroll 2
            for (int s2 = 0; s2 < 12; ++s2) {
                int kb = kh * 12 + s2;
                unsigned pa[8] = {0,0,0,0,0,0,0,0};
                if (col < 8) {
                    const uint4* q0 = (const uint4*)&s_tP[col * 776 + kb * 32 + grp * 8];
                    uint4 x0 = q0[0], x1 = q0[1];
                    pa[0]=x0.x; pa[1]=x0.y; pa[2]=x0.z; pa[3]=x0.w;
                    pa[4]=x1.x; pa[5]=x1.y; pa[6]=x1.z; pa[7]=x1.w;
                }
                bf16x8 ah, al; unpack_frags(pa, ah, al);
                int fo = ((rt * 24 + kb) * 64 + lane) * 8;
                bf16x8 bh = *(const bf16x8*)&W2H[fo];
                bf16x8 bl = *(const bf16x8*)&W2L[fo];
                aHH = mfma16(ah, bh, aHH);
                aLH = mfma16(al, bh, aLH);
                aHL = mfma16(ah, bl, aHL);
                aLL = mfma16(al, bl, aLL);
            }
            f32x4 accG;
#pragma unroll
            for (int reg = 0; reg < 4; ++reg) accG[reg] = (aHH[reg] + aLH[reg]) + (aHL[reg] + aLL[reg]);
            float* dst = (kh == 0) ? s_G0 : s_G1;
            if (grp < 2) {
#pragma unroll
                for (int reg = 0; reg < 4; ++reg)
                    dst[(grp * 4 + reg) * 96 + rt * 16 + col] = accG[reg];
            }
        }
        __syncthreads();                                   // B7
        // P10: GWq partials + S/Mi register updates (G = G0+G1)
        { int oo = tid % 192, q = tid / 192; int jg = oo / C3, cc = oo % C3;
          float a = 0.f;
          for (int f = q * 24; f < q * 24 + 24; ++f)
              a += (s_G0[jg * 96 + f] + s_G1[jg * 96 + f]) * s_Wq[f * C3 + cc];
          s_scrB[tid] = a; }
        {
            float tj[8], vj[8];
#pragma unroll
            for (int j = 0; j < 8; ++j) { tj[j] = s_tsum[j * 96 + de]; vj[j] = s_v[j * 96 + de]; }
            float sn[12], r2[12];
#pragma unroll
            for (int ii = 0; ii < 12; ++ii) { sn[ii] = 0.f; r2[ii] = rb2[ii]; }
#pragma unroll
            for (int j = 0; j < 8; ++j) {
                const float4* vp = (const float4*)&s_v[j * 96 + ef0];
                const float4* g0 = (const float4*)&s_G0[j * 96 + ef0];
                const float4* g1 = (const float4*)&s_G1[j * 96 + ef0];
#pragma unroll
                for (int q4 = 0; q4 < 3; ++q4) {
                    float4 vv = vp[q4], ga = g0[q4], gb = g1[q4];
                    float gx = ga.x + gb.x, gy = ga.y + gb.y, gz = ga.z + gb.z, gw = ga.w + gb.w;
                    sn[q4*4+0] += tj[j]*vv.x; sn[q4*4+1] += tj[j]*vv.y;
                    sn[q4*4+2] += tj[j]*vv.z; sn[q4*4+3] += tj[j]*vv.w;
                    r2[q4*4+0] += vj[j]*gx; r2[q4*4+1] += vj[j]*gy;
                    r2[q4*4+2] += vj[j]*gz; r2[q4*4+3] += vj[j]*gw;
                }
            }
#pragma unroll
            for (int ii = 0; ii < 12; ++ii) {
                rS[ii] = a1 * rS[ii] + sn[ii];
                rMi[ii] += a3 * r2[ii];
            }
        }
        __syncthreads();                                   // B8
        // P12: rQ += a3*(v^T GWq + b2Wq), GWq from 4 partials
#pragma unroll
        for (int pp = 0; pp < 3; ++pp) {
            int o = tid + 768 * pp; int i = o / C3, c = o % C3;
            float a = s_b2Wq[c];
#pragma unroll
            for (int j = 0; j < 8; ++j) {
                float g = s_scrB[j * C3 + c] + s_scrB[192 + j * C3 + c]
                        + s_scrB[384 + j * C3 + c] + s_scrB[576 + j * C3 + c];
                a += s_v[j * 96 + i] * g;
            }
            rQ[pp] += a3 * a;
        }
        // no barrier: next P2 touches only s_scrA/s_xall/regs; B1 orders the rest
    }
}

// ================= Kernel B: Δy + Z + scan, 1 block per batch =================
__global__ __launch_bounds__(256, 1) void dy_kernel(
    const short* __restrict__ WrBH, const short* __restrict__ WrBL,
    const short* __restrict__ t2g, const short* __restrict__ vgb,
    const short* __restrict__ W3H, const short* __restrict__ W3L,
    const float* __restrict__ c0, const float* __restrict__ cbr,
    const float* __restrict__ a1p,
    float* __restrict__ out)
{
    __shared__ __attribute__((aligned(16))) short sPT[49152];  // [w][btl][r*32+dl*8+j]; later Dy planes
    __shared__ float sZ[1024];                                 // [t][64]
    const int tid = threadIdx.x;
    const int w = tid >> 6, lane = tid & 63, col = lane & 15, grp = lane >> 4;
    const int b = blockIdx.x;
    const float a1 = a1p[0];
    short* PTw = sPT + w * 12288;

    // A-frags: 2 pairs (4 t's: t = w*4 + {0,1,2,3}), pair-packed M=16
    bf16x8 Av[2][3];
#pragma unroll
    for (int pr = 0; pr < 2; ++pr)
#pragma unroll
        for (int kf = 0; kf < 3; ++kf) {
            int t = w * 4 + pr * 2 + (col >> 3);
            int j = col & 7;
            uint4 z = *(const uint4*)&vgb[((size_t)(t * B_ + b)) * 768 + j * 96 + kf * 32 + grp * 8];
            FragU F; F.u[0] = z.x; F.u[1] = z.y; F.u[2] = z.z; F.u[3] = z.w;
            Av[pr][kf] = F.f;
        }
    f32x4 accD[4][6];
#pragma unroll
    for (int btl = 0; btl < 4; ++btl)
#pragma unroll
        for (int rt = 0; rt < 6; ++rt) accD[btl][rt] = (f32x4){0.f,0.f,0.f,0.f};

    for (int g4 = 0; g4 < 24; ++g4) {
        for (int dl = 0; dl < 4; ++dl) {
            const int d = g4 * 4 + dl;
            f32x4 aP[2][6];
#pragma unroll
            for (int pr = 0; pr < 2; ++pr)
#pragma unroll
                for (int rt = 0; rt < 6; ++rt) aP[pr][rt] = (f32x4){0.f,0.f,0.f,0.f};
#pragma unroll
            for (int kf = 0; kf < 3; ++kf)
#pragma unroll
                for (int rt = 0; rt < 6; ++rt) {
                    size_t fo = ((size_t)(d * 18 + rt * 3 + kf) * 64 + lane) * 8;
                    bf16x8 bh = *(const bf16x8*)&WrBH[fo];
                    bf16x8 bl = *(const bf16x8*)&WrBL[fo];
#pragma unroll
                    for (int pr = 0; pr < 2; ++pr) {
                        aP[pr][rt] = mfma16(Av[pr][kf], bh, aP[pr][rt]);
                        aP[pr][rt] = mfma16(Av[pr][kf], bl, aP[pr][rt]);
                    }
                }
            // store PT: row m = grp*4+reg -> btl = pr*2 + (grp>>1), j = (grp&1)*4 + reg
#pragma unroll
            for (int pr = 0; pr < 2; ++pr) {
                int btl = pr * 2 + (grp >> 1);
#pragma unroll
                for (int rt = 0; rt < 6; ++rt) {
                    uint2 uu;
                    uu.x = (unsigned)(unsigned short)f2bf(aP[pr][rt][0]) |
                           ((unsigned)(unsigned short)f2bf(aP[pr][rt][1]) << 16);
                    uu.y = (unsigned)(unsigned short)f2bf(aP[pr][rt][2]) |
                           ((unsigned)(unsigned short)f2bf(aP[pr][rt][3]) << 16);
                    *(uint2*)&PTw[btl * 3072 + (rt * 16 + col) * 32 + dl * 8 + (grp & 1) * 4] = uu;
                }
            }
        }
        // GEMM2 per btl
#pragma unroll
        for (int btl = 0; btl < 4; ++btl) {
            FragU A2;
            if (col < 8) {
                int t = w * 4 + btl;
                uint4 z = *(const uint4*)&t2g[((size_t)(t * B_ + b)) * 6144 + col * 768 + (g4 * 4 + grp) * 8];
                A2.u[0] = z.x; A2.u[1] = z.y; A2.u[2] = z.z; A2.u[3] = z.w;
            } else { A2.u[0]=A2.u[1]=A2.u[2]=A2.u[3]=0; }
#pragma unroll
            for (int rt = 0; rt < 6; ++rt) {
                bf16x8 B2 = *(const bf16x8*)&PTw[btl * 3072 + (rt * 16 + col) * 32 + grp * 8];
                accD[btl][rt] = mfma16(A2.f, B2, accD[btl][rt]);
            }
        }
    }
    __syncthreads();
    // write Δy split planes: DyH/DyL [t][776]
    short* DyH = sPT;
    short* DyL = sPT + 16 * 776;
    if (grp < 2) {
#pragma unroll
        for (int btl = 0; btl < 4; ++btl) {
            int t = w * 4 + btl;
#pragma unroll
            for (int rt = 0; rt < 6; ++rt)
#pragma unroll
                for (int reg = 0; reg < 4; ++reg) {
                    short h, l; splitf(accD[btl][rt][reg], h, l);
                    int idx = t * 776 + (grp * 4 + reg) * 96 + rt * 16 + col;
                    DyH[idx] = h; DyL[idx] = l;
                }
        }
    }
    __syncthreads();
    // Z-GEMM: wave w handles o-tile w. A = Dy (split), B = W3 (split), 3 terms
    {
        f32x4 zHH = {0,0,0,0}, zLH = {0,0,0,0}, zHL = {0,0,0,0};
#pragma unroll 4
        for (int kb = 0; kb < 24; ++kb) {
            bf16x8 ah = *(const bf16x8*)&DyH[col * 776 + kb * 32 + grp * 8];
            bf16x8 al = *(const bf16x8*)&DyL[col * 776 + kb * 32 + grp * 8];
            int fo = ((w * 24 + kb) * 64 + lane) * 8;
            bf16x8 bh = *(const bf16x8*)&W3H[fo];
            bf16x8 bl = *(const bf16x8*)&W3L[fo];
            zHH = mfma16(ah, bh, zHH);
            zLH = mfma16(al, bh, zLH);
            zHL = mfma16(ah, bl, zHL);
        }
#pragma unroll
        for (int reg = 0; reg < 4; ++reg)
            sZ[(grp * 4 + reg) * 64 + w * 16 + col] = zHH[reg] + zLH[reg] + zHL[reg];
    }
    __syncthreads();
    // scan over t and store out
    if (tid < 64) {
        float u = c0[tid];
        const float cb = cbr[tid];
        for (int t = 0; t < T_; ++t) {
            u = a1 * u + sZ[t * 64 + tid];
            out[((size_t)(t * B_ + b)) * OUT_ + tid] = u + cb;
        }
    }
}

extern "C" void kernel_launch(void* const* d_in, const int* in_sizes, int n_in,
                              void* d_out, int out_size, void* d_ws, size_t ws_size,
                              hipStream_t stream) {
    const float* x         = (const float*)d_in[0];
    const float* Wqkv      = (const float*)d_in[1];
    const float* bqkv      = (const float*)d_in[2];
    const float* ln_g      = (const float*)d_in[3];
    const float* ln_b      = (const float*)d_in[4];
    const float* a1        = (const float*)d_in[5];
    const float* a2        = (const float*)d_in[6];
    const float* a3        = (const float*)d_in[7];
    const float* W2        = (const float*)d_in[8];
    const float* b2        = (const float*)d_in[9];
    const float* Wr        = (const float*)d_in[10];
    const float* br        = (const float*)d_in[11];
    const float* W3        = (const float*)d_in[12];
    const float* b3        = (const float*)d_in[13];
    const float* item_bias = (const float*)d_in[14];
    const float* rel_bias  = (const float*)d_in[15];
    float* out = (float*)d_out;

    char* ws = (char*)d_ws;
    short* WrBH = (short*)ws;                          // 1,769,472 B
    short* WrBL = (short*)(ws + 1769472);              // 1,769,472 B
    short* W2H  = (short*)(ws + 3538944);              //   147,456 B
    short* W2L  = (short*)(ws + 3686400);              //   147,456 B
    short* W3H  = (short*)(ws + 3833856);              //    98,304 B
    short* W3L  = (short*)(ws + 3932160);              //    98,304 B
    float* y0   = (float*)(ws + 4030464);              //     3,072 B
    float* c0   = (float*)(ws + 4033536);              //       256 B
    float* cbr  = (float*)(ws + 4033792);              //       256 B
    short* t2g  = (short*)(ws + 4034048);              // 25,165,824 B
    short* vgb  = (short*)(ws + 29199872);             //  3,145,728 B

    hipMemsetAsync(y0, 0, 3072, stream);
    hipLaunchKernelGGL(prep_wrB, dim3(3456), dim3(256), 0, stream, Wr, WrBH, WrBL);
    hipLaunchKernelGGL(prep_w2f, dim3(288), dim3(256), 0, stream, W2, W2H, W2L);
    hipLaunchKernelGGL(prep_w3f, dim3(192), dim3(256), 0, stream, W3, W3H, W3L);
    hipLaunchKernelGGL(y0_kernel, dim3(64), dim3(768), 0, stream, rel_bias, Wr, y0);
    hipLaunchKernelGGL(c0_kernel, dim3(1), dim3(256), 0, stream, y0, br, W3, b3, c0, cbr);
    hipLaunchKernelGGL(stm_rec, dim3(B_), dim3(768), 0, stream,
                       x, Wqkv, bqkv, ln_g, ln_b, a1, a2, a3,
                       b2, item_bias, rel_bias, W2H, W2L, t2g, vgb);
    hipLaunchKernelGGL(dy_kernel, dim3(B_), dim3(256), 0, stream,
                       WrBH, WrBL, t2g, vgb, W3H, W3L, c0, cbr, a1, out);
}

// Round 11
// 683.472 us; speedup vs baseline: 3.0738x; 2.0252x over previous
//
#include <hip/hip_runtime.h>
#include <math.h>

#define T_ 16
#define B_ 128
#define C3 24
#define OUT_ 64
#define EPS_ 1e-5f

typedef __attribute__((ext_vector_type(8))) short bf16x8;
typedef __attribute__((ext_vector_type(4))) float f32x4;

union FragU { unsigned u[4]; bf16x8 f; };

__device__ __forceinline__ short f2bf(float x) {
    unsigned u = __float_as_uint(x);
    return (short)((u + 0x7fffu + ((u >> 16) & 1u)) >> 16);
}
__device__ __forceinline__ unsigned packsplit(float x) {
    unsigned u = __float_as_uint(x);
    unsigned h = (u + 0x7fffu + ((u >> 16) & 1u)) & 0xffff0000u;
    float r = x - __uint_as_float(h);
    unsigned v = __float_as_uint(r);
    unsigned l = (v + 0x7fffu + ((v >> 16) & 1u)) >> 16;
    return h | l;
}
__device__ __forceinline__ void unpack_frags(const unsigned* p, bf16x8& hi, bf16x8& lo) {
    FragU H, L;
#pragma unroll
    for (int q = 0; q < 4; ++q) {
        H.u[q] = (p[2*q] >> 16) | (p[2*q+1] & 0xffff0000u);
        L.u[q] = (p[2*q] & 0xffffu) | (p[2*q+1] << 16);
    }
    hi = H.f; lo = L.f;
}
__device__ __forceinline__ f32x4 mfma16(bf16x8 a, bf16x8 b, f32x4 c) {
    return __builtin_amdgcn_mfma_f32_16x16x32_bf16(a, b, c, 0, 0, 0);
}
__device__ __forceinline__ void splitf(float x, short& h, short& l) {
    unsigned u = __float_as_uint(x);
    unsigned hb = (u + 0x7fffu + ((u >> 16) & 1u)) & 0xffff0000u;
    float res = x - __uint_as_float(hb);
    unsigned v = __float_as_uint(res);
    h = (short)(hb >> 16);
    l = (short)((v + 0x7fffu + ((v >> 16) & 1u)) >> 16);
}

// ---------- prep: Wr -> B-fragment-major hi/lo planes, per-d mini-GEMMs ----------
__global__ void prep_wrB(const float* __restrict__ Wr, short* __restrict__ H, short* __restrict__ L) {
    int idx = blockIdx.x * 256 + threadIdx.x;
    if (idx >= 884736) return;
    int jj = idx & 7, lane = (idx >> 3) & 63, f = idx >> 9;
    int kf = f % 3, rt = (f / 3) % 6, d = f / 18;
    int col = lane & 15, grp = lane >> 4;
    int e = kf * 32 + grp * 8 + jj;
    int r = rt * 16 + col;
    short h, l; splitf(Wr[(size_t)(d * 96 + e) * 96 + r], h, l);
    H[idx] = h; L[idx] = l;
}
// ---------- prep: W2 -> B-fragment-major hi/lo planes ----------
__global__ void prep_w2f(const float* __restrict__ W2, short* __restrict__ Fhi, short* __restrict__ Flo) {
    int idx = blockIdx.x * 256 + threadIdx.x;
    if (idx >= 73728) return;
    int j = idx & 7, lane = (idx >> 3) & 63, kb = (idx >> 9) % 24, rt = idx / (512 * 24);
    int col = lane & 15, grp = lane >> 4;
    int f = rt * 16 + col, k = kb * 32 + grp * 8 + j;
    short h, l; splitf(W2[(size_t)k * 96 + f], h, l);
    Fhi[idx] = h; Flo[idx] = l;
}
// ---------- prep: W3 -> B-fragment-major hi/lo planes ----------
__global__ void prep_w3f(const float* __restrict__ W3, short* __restrict__ H, short* __restrict__ L) {
    int idx = blockIdx.x * 256 + threadIdx.x;
    if (idx >= 49152) return;
    int jj = idx & 7, lane = (idx >> 3) & 63, kb = (idx >> 9) % 24, ot = idx / (512 * 24);
    int col = lane & 15, grp = lane >> 4;
    int k = kb * 32 + grp * 8 + jj, o = ot * 16 + col;
    short h, l; splitf(W3[(size_t)k * 64 + o], h, l);
    H[idx] = h; L[idx] = l;
}
// ---------- prep: y0 = sum_n rel_bias @ Wr (fp32), 64-block atomic ----------
__global__ __launch_bounds__(768, 1) void y0_kernel(const float* __restrict__ rel_bias,
                                                    const float* __restrict__ Wr,
                                                    float* __restrict__ y0) {
    __shared__ float s[768];
    const int n = blockIdx.x >> 3, sl = blockIdx.x & 7;
    const int tid = threadIdx.x;
    const int r = tid % 96, p = tid / 96;
    const float* rb = rel_bias + n * 9216 + sl * 1152;
    float acc = 0.f;
    for (int i = p * 144; i < p * 144 + 144; ++i)
        acc += rb[i] * Wr[(size_t)(sl * 1152 + i) * 96 + r];
    s[tid] = acc;
    __syncthreads();
    if (tid < 96) {
        float tot = 0.f;
        for (int q = 0; q < 8; ++q) tot += s[q * 96 + tid];
        atomicAdd(&y0[n * 96 + tid], tot);
    }
}
// ---------- prep: c0 = y0@W3, cbr = br@W3 + b3 ----------
__global__ __launch_bounds__(256, 1) void c0_kernel(const float* __restrict__ y0,
                                                    const float* __restrict__ br,
                                                    const float* __restrict__ W3,
                                                    const float* __restrict__ b3,
                                                    float* __restrict__ c0,
                                                    float* __restrict__ cbr) {
    __shared__ float sp[512];
    const int tid = threadIdx.x;
    const int o = tid & 63, q = tid >> 6;
    float a = 0.f, c = 0.f;
    for (int i = q * 192; i < q * 192 + 192; ++i) {
        float w = W3[(size_t)i * 64 + o];
        a += y0[i] * w;
        c += br[i % 96] * w;
    }
    sp[tid] = a; sp[256 + tid] = c;
    __syncthreads();
    if (tid < 64) {
        float aa = 0.f, cc = 0.f;
        for (int qq = 0; qq < 4; ++qq) { aa += sp[qq * 64 + tid]; cc += sp[256 + qq * 64 + tid]; }
        c0[tid] = aa;
        cbr[tid] = cc + b3[tid];
    }
}

// ================= Kernel A: recurrence only, 1 block per batch (R10, unchanged) =================
__global__ __launch_bounds__(768, 2) void stm_rec(
    const float* __restrict__ x, const float* __restrict__ Wqkv, const float* __restrict__ bqkv,
    const float* __restrict__ ln_g, const float* __restrict__ ln_b,
    const float* __restrict__ a1p, const float* __restrict__ a2p, const float* __restrict__ a3p,
    const float* __restrict__ b2,
    const float* __restrict__ item_bias, const float* __restrict__ rel_bias,
    const short* __restrict__ W2H, const short* __restrict__ W2L,
    short* __restrict__ t2g, short* __restrict__ vgb)
{
    __shared__ float s_xall[1536];
    __shared__ __attribute__((aligned(16))) float s_scr[2304];
    __shared__ float s_scrA[768];
    __shared__ float s_scrB[768];
    __shared__ __attribute__((aligned(16))) unsigned s_tP[8 * 776];
    __shared__ __attribute__((aligned(16))) short s_t2L[6144];
    __shared__ float s_Wq[2304], s_lng[2304], s_lnb[2304];
    __shared__ float s_tsum[768], s_v[768];
    __shared__ float s_G0[768], s_G1[768];
    __shared__ float s_xtWq[24], s_b2Wq[24], s_bq[24];
    __shared__ float s_b2v[96], s_Vtr[96];
    __shared__ float s_red[32];

    const int tid = threadIdx.x;
    const int b = blockIdx.x;
    const int wv = tid >> 6, lane = tid & 63, col = lane & 15, grp = lane >> 4;
    const float a1 = a1p[0], a2 = a2p[0], a3 = a3p[0];

    const int de = tid >> 3, ef0 = (tid & 7) * 12;
    float rMi[12], rS[12], rb2[12], rQ[3];
#pragma unroll
    for (int ii = 0; ii < 12; ++ii) {
        int idx = de * 96 + ef0 + ii;
        rMi[ii] = item_bias[idx];
        float ss = 0.f;
        for (int n = 0; n < 8; ++n) ss += rel_bias[n * 9216 + idx];
        rS[ii] = ss;
        rb2[ii] = b2[ef0 + ii];
    }

    for (int i = tid; i < 1536; i += 768)
        s_xall[i] = x[((size_t)(i / 96) * B_ + b) * 96 + (i % 96)];
    for (int i = tid; i < 2304; i += 768) {
        s_Wq[i] = Wqkv[i]; s_lng[i] = ln_g[i]; s_lnb[i] = ln_b[i];
    }
    if (tid < 24) s_bq[tid] = bqkv[tid];
    if (tid < 96) s_b2v[tid] = b2[tid];
    __syncthreads();
#pragma unroll
    for (int pp = 0; pp < 3; ++pp) {
        int o = tid + 768 * pp; int i = o / C3, c = o % C3;
        float acc = 0.f;
        const float* ib = item_bias + i * 96;
        for (int k = 0; k < 96; ++k) acc += ib[k] * s_Wq[k * C3 + c];
        rQ[pp] = acc;
    }
    { int c = tid % C3, p = tid / C3; float acc = 0.f;
      for (int k = 3 * p; k < 3 * p + 3; ++k) acc += s_b2v[k] * s_Wq[k * C3 + c];
      s_scrA[tid] = acc; }
    __syncthreads();
    if (tid < C3) { float a = 0.f; for (int p = 0; p < 32; ++p) a += s_scrA[p * C3 + tid]; s_b2Wq[tid] = a; }
    __syncthreads();

    for (int t = 0; t < T_; ++t) {
        const float* xt = s_xall + t * 96;
        {
            float xde = xt[de];
            const float4* xp = (const float4*)&xt[ef0];
            float4 x0 = xp[0], x1 = xp[1], x2 = xp[2];
            rMi[0] += xde * x0.x; rMi[1] += xde * x0.y; rMi[2] += xde * x0.z; rMi[3] += xde * x0.w;
            rMi[4] += xde * x1.x; rMi[5] += xde * x1.y; rMi[6] += xde * x1.z; rMi[7] += xde * x1.w;
            rMi[8] += xde * x2.x; rMi[9] += xde * x2.y; rMi[10] += xde * x2.z; rMi[11] += xde * x2.w;
        }
        { int c = tid % C3, p = tid / C3; float acc = 0.f;
          for (int k = 3 * p; k < 3 * p + 3; ++k) acc += xt[k] * s_Wq[k * C3 + c];
          s_scrA[tid] = acc; }
        __syncthreads();
        if (tid < C3) { float a = 0.f; for (int p = 0; p < 32; ++p) a += s_scrA[p * C3 + tid]; s_xtWq[tid] = a; }
        {
            float p12[12];
#pragma unroll
            for (int ii = 0; ii < 12; ++ii) p12[ii] = rMi[ii] * rS[ii];
#pragma unroll
            for (int ii = 0; ii < 12; ++ii) {
                p12[ii] += __shfl_xor(p12[ii], 8);
                p12[ii] += __shfl_xor(p12[ii], 16);
                p12[ii] += __shfl_xor(p12[ii], 32);
            }
            if ((lane >> 3) == 0) {
#pragma unroll
                for (int ii = 0; ii < 12; ++ii)
                    s_scr[768 + wv * 96 + (lane & 7) * 12 + ii] = p12[ii];
            }
        }
        __syncthreads();
        if (tid < 96) { float a = 0.f; for (int w = 0; w < 12; ++w) a += s_scr[768 + w * 96 + tid]; s_Vtr[tid] = a; }
#pragma unroll
        for (int pp = 0; pp < 3; ++pp) { int o = tid + 768 * pp; int i = o / C3, c = o % C3;
            rQ[pp] += xt[i] * s_xtWq[c]; }
        __syncthreads();
        {
            float ls = 0.f, lq = 0.f;
#pragma unroll
            for (int pp = 0; pp < 3; ++pp) {
                int o = tid + 768 * pp; int i = o / C3, c = o % C3;
                float qv = rQ[pp] + a2 * s_Vtr[i] * s_xtWq[c] + s_bq[c];
                s_scr[o] = qv; ls += qv; lq += qv * qv;
            }
            for (int off = 32; off > 0; off >>= 1) { ls += __shfl_down(ls, off); lq += __shfl_down(lq, off); }
            if (lane == 0) { s_red[wv] = ls; s_red[16 + wv] = lq; }
        }
        __syncthreads();
        {
            float S = 0.f, Qs = 0.f;
            for (int w = 0; w < 12; ++w) { S += s_red[w]; Qs += s_red[16 + w]; }
            float mu = S * (1.0f / 2304.f);
            float rstd = rsqrtf(Qs * (1.0f / 2304.f) - mu * mu + EPS_);
#pragma unroll
            for (int pp = 0; pp < 3; ++pp) {
                int o = tid + 768 * pp;
                s_scr[o] = (s_scr[o] - mu) * rstd * s_lng[o] + s_lnb[o];
            }
        }
        __syncthreads();
        { int j = tid / 96, e = tid % 96;
          float vv = s_scr[e * C3 + 16 + j];
          s_v[tid] = vv;
          vgb[((size_t)(t * B_ + b)) * 768 + tid] = f2bf(vv); }
        {
            int j = tid / 96, d = tid % 96;
            float kk = s_scr[d * C3 + 8 + j];
            float ts = 0.f;
#pragma unroll
            for (int n = 0; n < 8; ++n) {
                float tv = tanhf(s_scr[d * C3 + n] * kk);
                ts += tv;
                unsigned up = packsplit(tv);
                s_tP[j * 776 + n * 96 + d] = up;
                s_t2L[n * 768 + d * 8 + j] = (short)(up >> 16);
            }
            s_tsum[j * 96 + d] = ts;
        }
        __syncthreads();
        *(uint4*)&t2g[((size_t)(t * B_ + b)) * 6144 + tid * 8] = *(const uint4*)&s_t2L[tid * 8];
        {
            const int rt = wv % 6, kh = wv / 6;
            f32x4 aHH = {0,0,0,0}, aLH = {0,0,0,0}, aHL = {0,0,0,0}, aLL = {0,0,0,0};
#pragma unroll 2
            for (int s2 = 0; s2 < 12; ++s2) {
                int kb = kh * 12 + s2;
                unsigned pa[8] = {0,0,0,0,0,0,0,0};
                if (col < 8) {
                    const uint4* q0 = (const uint4*)&s_tP[col * 776 + kb * 32 + grp * 8];
                    uint4 x0 = q0[0], x1 = q0[1];
                    pa[0]=x0.x; pa[1]=x0.y; pa[2]=x0.z; pa[3]=x0.w;
                    pa[4]=x1.x; pa[5]=x1.y; pa[6]=x1.z; pa[7]=x1.w;
                }
                bf16x8 ah, al; unpack_frags(pa, ah, al);
                int fo = ((rt * 24 + kb) * 64 + lane) * 8;
                bf16x8 bh = *(const bf16x8*)&W2H[fo];
                bf16x8 bl = *(const bf16x8*)&W2L[fo];
                aHH = mfma16(ah, bh, aHH);
                aLH = mfma16(al, bh, aLH);
                aHL = mfma16(ah, bl, aHL);
                aLL = mfma16(al, bl, aLL);
            }
            f32x4 accG;
#pragma unroll
            for (int reg = 0; reg < 4; ++reg) accG[reg] = (aHH[reg] + aLH[reg]) + (aHL[reg] + aLL[reg]);
            float* dst = (kh == 0) ? s_G0 : s_G1;
            if (grp < 2) {
#pragma unroll
                for (int reg = 0; reg < 4; ++reg)
                    dst[(grp * 4 + reg) * 96 + rt * 16 + col] = accG[reg];
            }
        }
        __syncthreads();
        { int oo = tid % 192, q = tid / 192; int jg = oo / C3, cc = oo % C3;
          float a = 0.f;
          for (int f = q * 24; f < q * 24 + 24; ++f)
              a += (s_G0[jg * 96 + f] + s_G1[jg * 96 + f]) * s_Wq[f * C3 + cc];
          s_scrB[tid] = a; }
        {
            float tj[8], vj[8];
#pragma unroll
            for (int j = 0; j < 8; ++j) { tj[j] = s_tsum[j * 96 + de]; vj[j] = s_v[j * 96 + de]; }
            float sn[12], r2[12];
#pragma unroll
            for (int ii = 0; ii < 12; ++ii) { sn[ii] = 0.f; r2[ii] = rb2[ii]; }
#pragma unroll
            for (int j = 0; j < 8; ++j) {
                const float4* vp = (const float4*)&s_v[j * 96 + ef0];
                const float4* g0 = (const float4*)&s_G0[j * 96 + ef0];
                const float4* g1 = (const float4*)&s_G1[j * 96 + ef0];
#pragma unroll
                for (int q4 = 0; q4 < 3; ++q4) {
                    float4 vv = vp[q4], ga = g0[q4], gb = g1[q4];
                    float gx = ga.x + gb.x, gy = ga.y + gb.y, gz = ga.z + gb.z, gw = ga.w + gb.w;
                    sn[q4*4+0] += tj[j]*vv.x; sn[q4*4+1] += tj[j]*vv.y;
                    sn[q4*4+2] += tj[j]*vv.z; sn[q4*4+3] += tj[j]*vv.w;
                    r2[q4*4+0] += vj[j]*gx; r2[q4*4+1] += vj[j]*gy;
                    r2[q4*4+2] += vj[j]*gz; r2[q4*4+3] += vj[j]*gw;
                }
            }
#pragma unroll
            for (int ii = 0; ii < 12; ++ii) {
                rS[ii] = a1 * rS[ii] + sn[ii];
                rMi[ii] += a3 * r2[ii];
            }
        }
        __syncthreads();
#pragma unroll
        for (int pp = 0; pp < 3; ++pp) {
            int o = tid + 768 * pp; int i = o / C3, c = o % C3;
            float a = s_b2Wq[c];
#pragma unroll
            for (int j = 0; j < 8; ++j) {
                float g = s_scrB[j * C3 + c] + s_scrB[192 + j * C3 + c]
                        + s_scrB[384 + j * C3 + c] + s_scrB[576 + j * C3 + c];
                a += s_v[j * 96 + i] * g;
            }
            rQ[pp] += a3 * a;
        }
    }
}

// ============ Kernel B: Δy + Z, barrier-free band-partitioned, 8 bt/block ============
// 256 blocks x 384 threads (6 waves). wave = rt band. Pair-packed M=16 GEMM1.
__global__ __launch_bounds__(384, 1) void dy_kernel(
    const short* __restrict__ WrBH, const short* __restrict__ WrBL,
    const short* __restrict__ t2g, const short* __restrict__ vgb,
    const short* __restrict__ W3H, const short* __restrict__ W3L,
    float* __restrict__ zbuf)
{
    __shared__ __attribute__((aligned(16))) short s_mem[30720];  // PT: 6 waves x 5120; Dy overlay
    const int tid = threadIdx.x;
    const int wv = tid >> 6, lane = tid & 63, col = lane & 15, grp = lane >> 4;
    const int b = blockIdx.x >> 1;
    const int th = (blockIdx.x & 1) * 8;   // this block's 8 t's
    const int rt = wv;
    short* PTw = s_mem + wv * 5120;        // [btl(8)][col(16)*40 + k(32)]

    // GEMM1 A-frags: 4 pairs x 3 kf, pair-packed rows (t_local = 2p + (col>>3), j = col&7)
    bf16x8 Av[4][3];
#pragma unroll
    for (int p = 0; p < 4; ++p)
#pragma unroll
        for (int kf = 0; kf < 3; ++kf) {
            int t = th + 2 * p + (col >> 3);
            int j = col & 7;
            uint4 z = *(const uint4*)&vgb[((size_t)(t * B_ + b)) * 768 + j * 96 + kf * 32 + grp * 8];
            FragU F; F.u[0] = z.x; F.u[1] = z.y; F.u[2] = z.z; F.u[3] = z.w;
            Av[p][kf] = F.f;
        }
    f32x4 accD[8];
#pragma unroll
    for (int btl = 0; btl < 8; ++btl) accD[btl] = (f32x4){0.f, 0.f, 0.f, 0.f};

    for (int d = 0; d < 96; ++d) {
        const int dl = d & 3;
        // B-frags for this wave's rt band straight from L2 (disjoint bands across waves)
        bf16x8 bh[3], bl[3];
#pragma unroll
        for (int kf = 0; kf < 3; ++kf) {
            int fo = ((d * 18 + rt * 3 + kf) * 64 + lane) * 8;
            bh[kf] = *(const bf16x8*)&WrBH[fo];
            bl[kf] = *(const bf16x8*)&WrBL[fo];
        }
        // GEMM1: 4 pair-chains x 6 MFMAs
        f32x4 aPv[4];
#pragma unroll
        for (int p = 0; p < 4; ++p) aPv[p] = (f32x4){0.f, 0.f, 0.f, 0.f};
#pragma unroll
        for (int kf = 0; kf < 3; ++kf) {
#pragma unroll
            for (int p = 0; p < 4; ++p) aPv[p] = mfma16(Av[p][kf], bh[kf], aPv[p]);
#pragma unroll
            for (int p = 0; p < 4; ++p) aPv[p] = mfma16(Av[p][kf], bl[kf], aPv[p]);
        }
        // PT store (wave-private; rows m = grp*4+reg -> btl = 2p + (grp>>1), j0 = (grp&1)*4)
        {
            const int j0 = (grp & 1) * 4;
            const int bo = grp >> 1;
#pragma unroll
            for (int p = 0; p < 4; ++p) {
                int btl = 2 * p + bo;
                uint2 uu;
                uu.x = (unsigned)(unsigned short)f2bf(aPv[p][0]) |
                       ((unsigned)(unsigned short)f2bf(aPv[p][1]) << 16);
                uu.y = (unsigned)(unsigned short)f2bf(aPv[p][2]) |
                       ((unsigned)(unsigned short)f2bf(aPv[p][3]) << 16);
                *(uint2*)&PTw[btl * 640 + col * 40 + dl * 8 + j0] = uu;
            }
        }
        // GEMM2 each 4 d's (wave-local PT; no barrier needed)
        if (dl == 3) {
            const int g4 = d >> 2;
#pragma unroll
            for (int btl = 0; btl < 8; ++btl) {
                FragU A2;
                if (col < 8) {
                    int t = th + btl;
                    uint4 z = *(const uint4*)&t2g[((size_t)(t * B_ + b)) * 6144 + col * 768 + g4 * 32 + grp * 8];
                    A2.u[0] = z.x; A2.u[1] = z.y; A2.u[2] = z.z; A2.u[3] = z.w;
                } else { A2.u[0] = A2.u[1] = A2.u[2] = A2.u[3] = 0; }
                bf16x8 B2 = *(const bf16x8*)&PTw[btl * 640 + col * 40 + grp * 8];
                accD[btl] = mfma16(A2.f, B2, accD[btl]);
            }
        }
    }
    __syncthreads();
    // Δy split planes (overlay PT region): Dy[btl][n*96+r], rows n = grp*4+reg < 8
    short* DyH = s_mem;
    short* DyL = s_mem + 6208;   // 8*776
    if (grp < 2) {
#pragma unroll
        for (int btl = 0; btl < 8; ++btl)
#pragma unroll
            for (int reg = 0; reg < 4; ++reg) {
                short h, l; splitf(accD[btl][reg], h, l);
                int idx = btl * 776 + (grp * 4 + reg) * 96 + rt * 16 + col;
                DyH[idx] = h; DyL[idx] = l;
            }
    }
    __syncthreads();
    // Z-GEMM: waves 0..3 = o-tiles; A rows = btl (col<8), K=768, split 3-term
    if (wv < 4) {
        const int ot = wv;
        f32x4 zHH = {0,0,0,0}, zLH = {0,0,0,0}, zHL = {0,0,0,0};
#pragma unroll 4
        for (int kb = 0; kb < 24; ++kb) {
            bf16x8 ah = *(const bf16x8*)&DyH[col * 776 + kb * 32 + grp * 8];
            bf16x8 al = *(const bf16x8*)&DyL[col * 776 + kb * 32 + grp * 8];
            int fo = ((ot * 24 + kb) * 64 + lane) * 8;
            bf16x8 bh = *(const bf16x8*)&W3H[fo];
            bf16x8 bl = *(const bf16x8*)&W3L[fo];
            zHH = mfma16(ah, bh, zHH);
            zLH = mfma16(al, bh, zLH);
            zHL = mfma16(ah, bl, zHL);
        }
        if (grp < 2) {
#pragma unroll
            for (int reg = 0; reg < 4; ++reg) {
                int m = grp * 4 + reg;     // = btl
                zbuf[((size_t)(th + m) * B_ + b) * OUT_ + ot * 16 + col] =
                    zHH[reg] + zLH[reg] + zHL[reg];
            }
        }
    }
}

// ================= Kernel C: 16-step scan + store, 1 wave per batch =================
__global__ __launch_bounds__(64, 1) void out_scan(
    const float* __restrict__ zbuf, const float* __restrict__ c0,
    const float* __restrict__ cbr, const float* __restrict__ a1p,
    float* __restrict__ out)
{
    const int b = blockIdx.x, o = threadIdx.x;
    const float a1 = a1p[0];
    float u = c0[o];
    const float cb = cbr[o];
    for (int t = 0; t < T_; ++t) {
        u = a1 * u + zbuf[((size_t)t * B_ + b) * OUT_ + o];
        out[((size_t)(t * B_ + b)) * OUT_ + o] = u + cb;
    }
}

extern "C" void kernel_launch(void* const* d_in, const int* in_sizes, int n_in,
                              void* d_out, int out_size, void* d_ws, size_t ws_size,
                              hipStream_t stream) {
    const float* x         = (const float*)d_in[0];
    const float* Wqkv      = (const float*)d_in[1];
    const float* bqkv      = (const float*)d_in[2];
    const float* ln_g      = (const float*)d_in[3];
    const float* ln_b      = (const float*)d_in[4];
    const float* a1        = (const float*)d_in[5];
    const float* a2        = (const float*)d_in[6];
    const float* a3        = (const float*)d_in[7];
    const float* W2        = (const float*)d_in[8];
    const float* b2        = (const float*)d_in[9];
    const float* Wr        = (const float*)d_in[10];
    const float* br        = (const float*)d_in[11];
    const float* W3        = (const float*)d_in[12];
    const float* b3        = (const float*)d_in[13];
    const float* item_bias = (const float*)d_in[14];
    const float* rel_bias  = (const float*)d_in[15];
    float* out = (float*)d_out;

    char* ws = (char*)d_ws;
    short* WrBH = (short*)ws;                          // 1,769,472 B
    short* WrBL = (short*)(ws + 1769472);              // 1,769,472 B
    short* W2H  = (short*)(ws + 3538944);              //   147,456 B
    short* W2L  = (short*)(ws + 3686400);              //   147,456 B
    short* W3H  = (short*)(ws + 3833856);              //    98,304 B
    short* W3L  = (short*)(ws + 3932160);              //    98,304 B
    float* y0   = (float*)(ws + 4030464);              //     3,072 B
    float* c0   = (float*)(ws + 4033536);              //       256 B
    float* cbr  = (float*)(ws + 4033792);              //       256 B
    short* t2g  = (short*)(ws + 4034048);              // 25,165,824 B
    short* vgb  = (short*)(ws + 29199872);             //  3,145,728 B
    float* zbuf = (float*)(ws + 32345600);             //    524,288 B

    hipMemsetAsync(y0, 0, 3072, stream);
    hipLaunchKernelGGL(prep_wrB, dim3(3456), dim3(256), 0, stream, Wr, WrBH, WrBL);
    hipLaunchKernelGGL(prep_w2f, dim3(288), dim3(256), 0, stream, W2, W2H, W2L);
    hipLaunchKernelGGL(prep_w3f, dim3(192), dim3(256), 0, stream, W3, W3H, W3L);
    hipLaunchKernelGGL(y0_kernel, dim3(64), dim3(768), 0, stream, rel_bias, Wr, y0);
    hipLaunchKernelGGL(c0_kernel, dim3(1), dim3(256), 0, stream, y0, br, W3, b3, c0, cbr);
    hipLaunchKernelGGL(stm_rec, dim3(B_), dim3(768), 0, stream,
                       x, Wqkv, bqkv, ln_g, ln_b, a1, a2, a3,
                       b2, item_bias, rel_bias, W2H, W2L, t2g, vgb);
    hipLaunchKernelGGL(dy_kernel, dim3(256), dim3(384), 0, stream,
                       WrBH, WrBL, t2g, vgb, W3H, W3L, zbuf);
    hipLaunchKernelGGL(out_scan, dim3(B_), dim3(64), 0, stream,
                       zbuf, c0, cbr, a1, out);
}